// Round 10
// baseline (952.440 us; speedup 1.0000x reference)
//
#include <hip/hip_runtime.h>
#include <cstdint>
#include <cstddef>

#define D 1024
#define BATCH 16384
#define NLAYERS 18
#define RR 32

typedef __attribute__((ext_vector_type(8))) __bf16 bf16x8;
typedef __attribute__((ext_vector_type(4))) float f32x4;
typedef __attribute__((address_space(3))) void lds_void_t;
typedef __attribute__((address_space(1))) void gmem_void_t;

union bfpack { unsigned short us[8]; int4 v; };

__device__ __forceinline__ unsigned short f2bf(float f) {
    unsigned int b = __builtin_bit_cast(unsigned int, f);
    b += 0x7fffu + ((b >> 16) & 1u);
    return (unsigned short)(b >> 16);
}
__device__ __forceinline__ float bf2f(unsigned short u) {
    return __builtin_bit_cast(float, (unsigned int)u << 16);
}

// ---------------------------------------------------------------------------
// lora_dequant: weff = (q/15*2-1)*scale + 4*(lb@la), bf16, fused.
// R9 post-mortem: occupancy fix didn't move dur (48us, nothing busy) ->
// latency-serialized dequant loop. Fix: prefetch ALL q (16 int4) + scales
// (8 f32) into registers at kernel entry; HBM latency hides under the
// la/lb staging + MFMA phase. Dequant loop is then pure compute+store.
// ---------------------------------------------------------------------------
__global__ __launch_bounds__(256) void lora_dequant(
    const float* __restrict__ la, const float* __restrict__ lb,
    const int* __restrict__ q, const float* __restrict__ scales,
    unsigned short* __restrict__ weff) {
    __shared__ __align__(16) char lds[33792];
    unsigned short (*lbs)[40] = (unsigned short (*)[40])lds;            // [64][40]
    unsigned short (*lat)[40] = (unsigned short (*)[40])(lds + 5120);   // [256][40]
    unsigned short (*out_s)[264] = (unsigned short (*)[264])lds;        // [64][264] aliases
    const int b = blockIdx.x;                  // 18*16*4
    const int li = b >> 6;
    const int o0 = ((b >> 2) & 15) << 6;
    const int i0 = (b & 3) << 8;
    const int t = threadIdx.x;

    // ---- prefetch q + scales for all 8 dequant iterations (regs) ----
    int4 qreg[16];
    float sreg[8];
#pragma unroll
    for (int iter = 0; iter < 8; ++iter) {
        const int idx = (iter << 8) + t;
        const int row = idx >> 5, c8 = (idx & 31) << 3;
        const size_t grow = (size_t)li * D + o0 + row;
        const int col = i0 + c8;
        const int* qp = q + grow * D + col;
        qreg[2 * iter] = ((const int4*)qp)[0];
        qreg[2 * iter + 1] = ((const int4*)qp)[1];
        sreg[iter] = scales[grow * (D / 16) + (col >> 4)];
    }

    {   // lbs: 64x32 f32 -> bf16
        const int row = t >> 2, qt = t & 3;
        const float* src = lb + ((size_t)(li * D) + o0 + row) * RR + qt * 8;
        float4 v0 = ((const float4*)src)[0], v1 = ((const float4*)src)[1];
        bfpack u;
        u.us[0] = f2bf(v0.x); u.us[1] = f2bf(v0.y); u.us[2] = f2bf(v0.z); u.us[3] = f2bf(v0.w);
        u.us[4] = f2bf(v1.x); u.us[5] = f2bf(v1.y); u.us[6] = f2bf(v1.z); u.us[7] = f2bf(v1.w);
        *(int4*)&lbs[row][qt * 8] = u.v;
    }
    {   // lat[col][r] = bf16(la[li][r][i0+col])
        const int col = t;
#pragma unroll 8
        for (int r = 0; r < 32; ++r)
            lat[col][r] = f2bf(la[((size_t)li * RR + r) * D + i0 + col]);
    }
    __syncthreads();

    // fragment loads (regs), then barrier BEFORE aliased out_s writes
    const int wid = t >> 6, lane = t & 63;
    const int l15 = lane & 15, kgrp = lane >> 4;
    const int wrow = (wid >> 1) << 5;   // 0/32
    const int wcol = (wid & 1) << 7;    // 0/128
    bf16x8 a[2], bb[8];
#pragma unroll
    for (int f = 0; f < 2; ++f)
        a[f] = *(const bf16x8*)&lbs[wrow + (f << 4) + l15][kgrp << 3];
#pragma unroll
    for (int g = 0; g < 8; ++g)
        bb[g] = *(const bf16x8*)&lat[wcol + (g << 4) + l15][kgrp << 3];
    __syncthreads();   // all waves' LDS reads complete before aliasing

    {   // MFMA + write lora tile to out_s (aliased region)
        f32x4 acc[2][8];
#pragma unroll
        for (int i = 0; i < 2; ++i)
#pragma unroll
            for (int j = 0; j < 8; ++j) acc[i][j] = 0.0f;
#pragma unroll
        for (int mi = 0; mi < 2; ++mi)
#pragma unroll
            for (int ni = 0; ni < 8; ++ni)
                acc[mi][ni] = __builtin_amdgcn_mfma_f32_16x16x32_bf16(
                    a[mi], bb[ni], acc[mi][ni], 0, 0, 0);
        // C/D: col = l15, row = kgrp*4 + r
#pragma unroll
        for (int mi = 0; mi < 2; ++mi) {
            const int row = wrow + (mi << 4) + (kgrp << 2);
#pragma unroll
            for (int ni = 0; ni < 8; ++ni) {
                const int col = wcol + (ni << 4) + l15;
#pragma unroll
                for (int r = 0; r < 4; ++r)
                    out_s[row + r][col] = f2bf(4.0f * acc[mi][ni][r]);
            }
        }
    }
    __syncthreads();

    // dequant from registers: pure compute + coalesced store
    const float c = 2.0f / 15.0f;
#pragma unroll
    for (int iter = 0; iter < 8; ++iter) {
        const int idx = (iter << 8) + t;
        const int row = idx >> 5, c8 = (idx & 31) << 3;
        const size_t grow = (size_t)li * D + o0 + row;
        const int col = i0 + c8;
        const float s = sreg[iter];
        bfpack lo;
        lo.v = *(const int4*)&out_s[row][c8];
        int qa[8] = {qreg[2 * iter].x, qreg[2 * iter].y, qreg[2 * iter].z, qreg[2 * iter].w,
                     qreg[2 * iter + 1].x, qreg[2 * iter + 1].y, qreg[2 * iter + 1].z, qreg[2 * iter + 1].w};
        bfpack u;
#pragma unroll
        for (int j = 0; j < 8; ++j)
            u.us[j] = f2bf(((float)qa[j] * c - 1.0f) * s + bf2f(lo.us[j]));
        *(int4*)(weff + grow * D + col) = u.v;
    }
}

// xb = bf16(x)
__global__ __launch_bounds__(256) void init_xb(const float* __restrict__ x,
                                               unsigned short* __restrict__ xb) {
    const size_t i = (size_t)blockIdx.x * 256 + threadIdx.x;
    float4 v = ((const float4*)x)[i];
    ushort4 u;
    u.x = f2bf(v.x); u.y = f2bf(v.y); u.z = f2bf(v.z); u.w = f2bf(v.w);
    ((ushort4*)xb)[i] = u;
}

#define SBAR() do { asm volatile("" ::: "memory"); __builtin_amdgcn_s_barrier(); asm volatile("" ::: "memory"); } while (0)

// ---------------------------------------------------------------------------
// gemm256 (v4): 256x256 tile, 8 waves, 16x16x32 MFMA, 4-slot ring, depth-3
// counted vmcnt(8). [R3/R7-verified ~37us @ K=1024 — structural ceiling;
// 32x32 MFMA (R4) and 2-block/CU 256x128 (R9) both regressed].
// mode 0: outb=bf16(relu(v)); mode 1: outb=bf16(v);
// mode 2: outf = v + bf2f(hb)  (fused final residual add, f32 out).
// ---------------------------------------------------------------------------
__global__ __launch_bounds__(512, 2) void gemm256(
    const unsigned short* __restrict__ xb, const unsigned short* __restrict__ w,
    const float* __restrict__ bias,
    unsigned short* __restrict__ outb, const unsigned short* __restrict__ hb,
    float* __restrict__ outf, int mode) {
    __shared__ __align__(16) char smem[131072];
    const int tid = threadIdx.x;
    const int wid = tid >> 6, lane = tid & 63;
    const int bid = blockIdx.x + (blockIdx.y << 2);
    const int xcd = bid & 7, slot = bid >> 3;
    const int m0 = ((xcd << 3) + (slot >> 2)) << 8;
    const int n0 = (slot & 3) << 8;
    const int l15 = lane & 15, kgrp = lane >> 4;
    const int wrow = (wid >> 2) << 7;
    const int wcol = (wid & 3) << 6;

    f32x4 acc[8][4];
#pragma unroll
    for (int i = 0; i < 8; ++i)
#pragma unroll
        for (int j = 0; j < 4; ++j) acc[i][j] = 0.0f;

#define STAGE_HALF(hs, i_)                                                     \
    do {                                                                       \
        const int k0_ = (hs) << 5;                                             \
        char* sA_ = smem + ((hs) & 3) * 32768;                                 \
        const int off_ = (i_) * 8192 + (tid << 4);                             \
        const int r_ = off_ >> 6;                                              \
        const int j_ = ((off_ >> 4) & 3) ^ ((r_ >> 1) & 3);                    \
        const unsigned short* ga_ = xb + (size_t)(m0 + r_) * D + k0_ + (j_ << 3); \
        const unsigned short* gb_ = w + (size_t)(n0 + r_) * D + k0_ + (j_ << 3);  \
        char* lA_ = sA_ + (i_) * 8192 + (wid << 10);                           \
        __builtin_amdgcn_global_load_lds((const gmem_void_t*)ga_, (lds_void_t*)lA_, 16, 0, 0);          \
        __builtin_amdgcn_global_load_lds((const gmem_void_t*)gb_, (lds_void_t*)(lA_ + 16384), 16, 0, 0); \
    } while (0)

    STAGE_HALF(0, 0); STAGE_HALF(0, 1);
    STAGE_HALF(1, 0); STAGE_HALF(1, 1);
    STAGE_HALF(2, 0); STAGE_HALF(2, 1);
    asm volatile("s_waitcnt vmcnt(8)" ::: "memory");
    SBAR();

    for (int h = 0; h < 32; ++h) {
        const char* sA = smem + (h & 3) * 32768;
        const char* sB = sA + 16384;
        bf16x8 a[8], b[4];
#pragma unroll
        for (int f = 0; f < 4; ++f) {
            const int r = wrow + (f << 4) + l15;
            a[f] = *(const bf16x8*)(sA + (r << 6) + ((kgrp ^ ((r >> 1) & 3)) << 4));
        }
#pragma unroll
        for (int g = 0; g < 4; ++g) {
            const int r = wcol + (g << 4) + l15;
            b[g] = *(const bf16x8*)(sB + (r << 6) + ((kgrp ^ ((r >> 1) & 3)) << 4));
        }
        if (h < 29) STAGE_HALF(h + 3, 0);
        SBAR();
        asm volatile("s_waitcnt lgkmcnt(0)" ::: "memory");
        __builtin_amdgcn_s_setprio(1);
#pragma unroll
        for (int mi = 0; mi < 4; ++mi)
#pragma unroll
            for (int ni = 0; ni < 4; ++ni)
                acc[mi][ni] = __builtin_amdgcn_mfma_f32_16x16x32_bf16(
                    a[mi], b[ni], acc[mi][ni], 0, 0, 0);
        __builtin_amdgcn_s_setprio(0);
        SBAR();
#pragma unroll
        for (int f = 4; f < 8; ++f) {
            const int r = wrow + (f << 4) + l15;
            a[f] = *(const bf16x8*)(sA + (r << 6) + ((kgrp ^ ((r >> 1) & 3)) << 4));
        }
        if (h < 29) {
            STAGE_HALF(h + 3, 1);
            asm volatile("s_waitcnt vmcnt(8)" ::: "memory");
        } else if (h == 29) {
            asm volatile("s_waitcnt vmcnt(4)" ::: "memory");
        } else if (h == 30) {
            asm volatile("s_waitcnt vmcnt(0)" ::: "memory");
        }
        SBAR();
        asm volatile("s_waitcnt lgkmcnt(0)" ::: "memory");
        __builtin_amdgcn_s_setprio(1);
#pragma unroll
        for (int mi = 4; mi < 8; ++mi)
#pragma unroll
            for (int ni = 0; ni < 4; ++ni)
                acc[mi][ni] = __builtin_amdgcn_mfma_f32_16x16x32_bf16(
                    a[mi], b[ni], acc[mi][ni], 0, 0, 0);
        __builtin_amdgcn_s_setprio(0);
        SBAR();
    }

    const int crow = kgrp << 2;
    float bv[4];
#pragma unroll
    for (int ni = 0; ni < 4; ++ni) bv[ni] = bias[n0 + wcol + (ni << 4) + l15];
#pragma unroll
    for (int mi = 0; mi < 8; ++mi) {
        const int rbase = m0 + wrow + (mi << 4) + crow;
#pragma unroll
        for (int ni = 0; ni < 4; ++ni) {
            const int col = n0 + wcol + (ni << 4) + l15;
#pragma unroll
            for (int r = 0; r < 4; ++r) {
                float v = acc[mi][ni][r] + bv[ni];
                const size_t o = (size_t)(rbase + r) * D + col;
                if (mode == 0) {
                    v = v > 0.0f ? v : 0.0f;
                    outb[o] = f2bf(v);
                } else if (mode == 1) {
                    outb[o] = f2bf(v);
                } else {
                    outf[o] = v + bf2f(hb[o]);
                }
            }
        }
    }
}

// hb = bf16(LN(hb + vb)) in place
__global__ __launch_bounds__(256) void resid_ln_b(
    unsigned short* __restrict__ hb, const unsigned short* __restrict__ vb,
    const float* __restrict__ gamma, const float* __restrict__ beta) {
    const int row = blockIdx.x;
    const int t = threadIdx.x;
    unsigned short* hr = hb + (size_t)row * D;
    ushort4 hv = ((const ushort4*)hr)[t];
    ushort4 vv = ((const ushort4*)(vb + (size_t)row * D))[t];
    float4 v;
    v.x = bf2f(hv.x) + bf2f(vv.x); v.y = bf2f(hv.y) + bf2f(vv.y);
    v.z = bf2f(hv.z) + bf2f(vv.z); v.w = bf2f(hv.w) + bf2f(vv.w);
    float s = v.x + v.y + v.z + v.w;
    float s2 = v.x * v.x + v.y * v.y + v.z * v.z + v.w * v.w;
#pragma unroll
    for (int off = 32; off > 0; off >>= 1) {
        s += __shfl_down(s, off);
        s2 += __shfl_down(s2, off);
    }
    __shared__ float red[8];
    const int wid = t >> 6, lane = t & 63;
    if (lane == 0) { red[wid] = s; red[wid + 4] = s2; }
    __syncthreads();
    s = red[0] + red[1] + red[2] + red[3];
    s2 = red[4] + red[5] + red[6] + red[7];
    const float mu = s * (1.0f / D);
    const float var = s2 * (1.0f / D) - mu * mu;
    const float rs = rsqrtf(var + 1e-5f);
    float4 g = ((const float4*)gamma)[t];
    float4 b = ((const float4*)beta)[t];
    ushort4 u;
    u.x = f2bf((v.x - mu) * rs * g.x + b.x);
    u.y = f2bf((v.y - mu) * rs * g.y + b.y);
    u.z = f2bf((v.z - mu) * rs * g.z + b.z);
    u.w = f2bf((v.w - mu) * rs * g.w + b.w);
    ((ushort4*)hr)[t] = u;
}

extern "C" void kernel_launch(void* const* d_in, const int* in_sizes, int n_in,
                              void* d_out, int out_size, void* d_ws, size_t ws_size,
                              hipStream_t stream) {
    const float* x      = (const float*)d_in[0];
    const int*   q      = (const int*)d_in[1];
    const float* scales = (const float*)d_in[2];
    const float* biases = (const float*)d_in[3];
    const float* la     = (const float*)d_in[4];
    const float* lb     = (const float*)d_in[5];
    const float* lng    = (const float*)d_in[6];
    const float* lnb    = (const float*)d_in[7];
    float* out = (float*)d_out;

    char* p = (char*)d_ws;
    unsigned short* weff = (unsigned short*)p; p += (size_t)NLAYERS * D * D * 2;
    unsigned short* xbA  = (unsigned short*)p; p += (size_t)BATCH * D * 2;
    unsigned short* xbB  = (unsigned short*)p; p += (size_t)BATCH * D * 2;
    unsigned short* xbC  = (unsigned short*)p;

    lora_dequant<<<NLAYERS * 16 * 4, 256, 0, stream>>>(la, lb, q, scales, weff);
    init_xb<<<BATCH * D / 4 / 256, 256, 0, stream>>>(x, xbA);

    dim3 ggrid(4, 64);
    for (int blk = 0; blk < 6; ++blk) {
        const int li = 3 * blk;
        gemm256<<<ggrid, 512, 0, stream>>>(xbA, weff + (size_t)li * D * D,
                                           biases + (size_t)li * D, xbB, nullptr, nullptr, 0);
        gemm256<<<ggrid, 512, 0, stream>>>(xbB, weff + (size_t)(li + 1) * D * D,
                                           biases + (size_t)(li + 1) * D, xbC, nullptr, nullptr, 0);
        if (blk < 5) {
            gemm256<<<ggrid, 512, 0, stream>>>(xbC, weff + (size_t)(li + 2) * D * D,
                                               biases + (size_t)(li + 2) * D, xbB, nullptr, nullptr, 1);
            resid_ln_b<<<BATCH, 256, 0, stream>>>(xbA, xbB,
                                                  lng + (size_t)blk * D, lnb + (size_t)blk * D);
        } else {
            gemm256<<<ggrid, 512, 0, stream>>>(xbC, weff + (size_t)(li + 2) * D * D,
                                               biases + (size_t)(li + 2) * D, nullptr, xbA, out, 2);
        }
    }
}

// Round 11
// 846.441 us; speedup vs baseline: 1.1252x; 1.1252x over previous
//
#include <hip/hip_runtime.h>
#include <cstdint>
#include <cstddef>

#define D 1024
#define BATCH 16384
#define NLAYERS 18
#define RR 32

typedef __attribute__((ext_vector_type(8))) __bf16 bf16x8;
typedef __attribute__((ext_vector_type(4))) float f32x4;
typedef __attribute__((address_space(3))) void lds_void_t;
typedef __attribute__((address_space(1))) void gmem_void_t;

union bfpack { unsigned short us[8]; int4 v; };

__device__ __forceinline__ unsigned short f2bf(float f) {
    unsigned int b = __builtin_bit_cast(unsigned int, f);
    b += 0x7fffu + ((b >> 16) & 1u);
    return (unsigned short)(b >> 16);
}
__device__ __forceinline__ float bf2f(unsigned short u) {
    return __builtin_bit_cast(float, (unsigned int)u << 16);
}

// ---------------------------------------------------------------------------
// lora_gemm: loraB[li][o][i] = 4 * sum_r lb[li][o][r] * la[li][r][i], bf16.
// [R7-measured: ~10us] Rank-32 MFMA GEMM, 256x256 tile, 8 waves, 1 K-step.
// ---------------------------------------------------------------------------
__global__ __launch_bounds__(512) void lora_gemm(
    const float* __restrict__ la, const float* __restrict__ lb,
    unsigned short* __restrict__ loraB) {
    __shared__ unsigned short lbs[256][40];
    __shared__ unsigned short lat[256][40];
    const int b = blockIdx.x;                 // 18*16
    const int li = b >> 4;
    const int o0 = ((b >> 2) & 3) << 8;
    const int i0 = (b & 3) << 8;
    const int t = threadIdx.x;

    {   // lbs[row][r] = bf16(lb[li][o0+row][r])
        const int row = t >> 1, half = t & 1;
        const float* src = lb + ((size_t)(li * D) + o0 + row) * RR + half * 16;
        bfpack u[2];
#pragma unroll
        for (int j = 0; j < 2; ++j) {
            float4 v0 = ((const float4*)src)[2 * j];
            float4 v1 = ((const float4*)src)[2 * j + 1];
            u[j].us[0] = f2bf(v0.x); u[j].us[1] = f2bf(v0.y);
            u[j].us[2] = f2bf(v0.z); u[j].us[3] = f2bf(v0.w);
            u[j].us[4] = f2bf(v1.x); u[j].us[5] = f2bf(v1.y);
            u[j].us[6] = f2bf(v1.z); u[j].us[7] = f2bf(v1.w);
        }
        *(int4*)&lbs[row][half * 16] = u[0].v;
        *(int4*)&lbs[row][half * 16 + 8] = u[1].v;
    }
    {   // lat[col][r] = bf16(la[li][r][i0+col])
        const int col = t >> 1, rhalf = t & 1;
#pragma unroll
        for (int rr = 0; rr < 16; ++rr) {
            const int r = rhalf * 16 + rr;
            lat[col][r] = f2bf(la[((size_t)li * RR + r) * D + i0 + col]);
        }
    }
    __syncthreads();

    const int wid = t >> 6, lane = t & 63;
    const int l15 = lane & 15, kgrp = lane >> 4;
    const int wrow = (wid >> 2) << 7;
    const int wcol = (wid & 3) << 6;

    bf16x8 a[8], bb[4];
#pragma unroll
    for (int f = 0; f < 8; ++f)
        a[f] = *(const bf16x8*)&lbs[wrow + (f << 4) + l15][kgrp << 3];
#pragma unroll
    for (int g = 0; g < 4; ++g)
        bb[g] = *(const bf16x8*)&lat[wcol + (g << 4) + l15][kgrp << 3];

    f32x4 acc[8][4];
#pragma unroll
    for (int i = 0; i < 8; ++i)
#pragma unroll
        for (int j = 0; j < 4; ++j) acc[i][j] = 0.0f;
#pragma unroll
    for (int mi = 0; mi < 8; ++mi)
#pragma unroll
        for (int ni = 0; ni < 4; ++ni)
            acc[mi][ni] = __builtin_amdgcn_mfma_f32_16x16x32_bf16(
                a[mi], bb[ni], acc[mi][ni], 0, 0, 0);

    unsigned short* dst = loraB + (size_t)li * D * D;
#pragma unroll
    for (int mi = 0; mi < 8; ++mi) {
        const int row = o0 + wrow + (mi << 4) + (kgrp << 2);
#pragma unroll
        for (int ni = 0; ni < 4; ++ni) {
            const int col = i0 + wcol + (ni << 4) + l15;
#pragma unroll
            for (int r = 0; r < 4; ++r)
                dst[(size_t)(row + r) * D + col] = f2bf(4.0f * acc[mi][ni][r]);
        }
    }
}

// ---------------------------------------------------------------------------
// dequant: weff = (q/15*2-1)*scale + loraB  [R7-measured: ~28us, ~5.5TB/s]
// ---------------------------------------------------------------------------
__global__ __launch_bounds__(256) void dequant(
    const int* __restrict__ q, const float* __restrict__ scales,
    const unsigned short* __restrict__ loraB, unsigned short* __restrict__ weff) {
    const size_t n8 = (size_t)NLAYERS * D * D / 8;
    const float c = 2.0f / 15.0f;
    for (size_t i = (size_t)blockIdx.x * 256 + threadIdx.x; i < n8;
         i += (size_t)gridDim.x * 256) {
        const size_t base = i << 3;
        const int* qp = q + base;
        int4 q0 = ((const int4*)qp)[0], q1 = ((const int4*)qp)[1];
        bfpack lo;
        lo.v = *(const int4*)(loraB + base);
        const float s = scales[base >> 4];
        int qa[8] = {q0.x, q0.y, q0.z, q0.w, q1.x, q1.y, q1.z, q1.w};
        bfpack u;
#pragma unroll
        for (int j = 0; j < 8; ++j)
            u.us[j] = f2bf(((float)qa[j] * c - 1.0f) * s + bf2f(lo.us[j]));
        *(int4*)(weff + base) = u.v;
    }
}

// xb = bf16(x)
__global__ __launch_bounds__(256) void init_xb(const float* __restrict__ x,
                                               unsigned short* __restrict__ xb) {
    const size_t i = (size_t)blockIdx.x * 256 + threadIdx.x;
    float4 v = ((const float4*)x)[i];
    ushort4 u;
    u.x = f2bf(v.x); u.y = f2bf(v.y); u.z = f2bf(v.z); u.w = f2bf(v.w);
    ((ushort4*)xb)[i] = u;
}

#define SBAR() do { asm volatile("" ::: "memory"); __builtin_amdgcn_s_barrier(); asm volatile("" ::: "memory"); } while (0)

// ---------------------------------------------------------------------------
// gemm256 (v4): 256x256 tile, 8 waves, 16x16x32 MFMA, 4-slot ring, depth-3
// counted vmcnt(8), XOR swizzle both-sides, setprio, XCD-chunked bid.
// [R3/R7/R8-measured ~37us @ K=1024 ≈ 930 TF — structural ceiling for this
// schedule; 32x32 MFMA (R4), 2-block/CU 256x128 (R9), epilogue fusion (R10)
// all regressed]. mode 0: outb=bf16(relu(v)); mode 1: outb=bf16(v).
// ---------------------------------------------------------------------------
__global__ __launch_bounds__(512, 2) void gemm256(
    const unsigned short* __restrict__ xb, const unsigned short* __restrict__ w,
    const float* __restrict__ bias,
    unsigned short* __restrict__ outb, int mode) {
    __shared__ __align__(16) char smem[131072];
    const int tid = threadIdx.x;
    const int wid = tid >> 6, lane = tid & 63;
    const int bid = blockIdx.x + (blockIdx.y << 2);
    const int xcd = bid & 7, slot = bid >> 3;
    const int m0 = ((xcd << 3) + (slot >> 2)) << 8;
    const int n0 = (slot & 3) << 8;
    const int l15 = lane & 15, kgrp = lane >> 4;
    const int wrow = (wid >> 2) << 7;
    const int wcol = (wid & 3) << 6;

    f32x4 acc[8][4];
#pragma unroll
    for (int i = 0; i < 8; ++i)
#pragma unroll
        for (int j = 0; j < 4; ++j) acc[i][j] = 0.0f;

#define STAGE_HALF(hs, i_)                                                     \
    do {                                                                       \
        const int k0_ = (hs) << 5;                                             \
        char* sA_ = smem + ((hs) & 3) * 32768;                                 \
        const int off_ = (i_) * 8192 + (tid << 4);                             \
        const int r_ = off_ >> 6;                                              \
        const int j_ = ((off_ >> 4) & 3) ^ ((r_ >> 1) & 3);                    \
        const unsigned short* ga_ = xb + (size_t)(m0 + r_) * D + k0_ + (j_ << 3); \
        const unsigned short* gb_ = w + (size_t)(n0 + r_) * D + k0_ + (j_ << 3);  \
        char* lA_ = sA_ + (i_) * 8192 + (wid << 10);                           \
        __builtin_amdgcn_global_load_lds((const gmem_void_t*)ga_, (lds_void_t*)lA_, 16, 0, 0);          \
        __builtin_amdgcn_global_load_lds((const gmem_void_t*)gb_, (lds_void_t*)(lA_ + 16384), 16, 0, 0); \
    } while (0)

    STAGE_HALF(0, 0); STAGE_HALF(0, 1);
    STAGE_HALF(1, 0); STAGE_HALF(1, 1);
    STAGE_HALF(2, 0); STAGE_HALF(2, 1);
    asm volatile("s_waitcnt vmcnt(8)" ::: "memory");
    SBAR();

    for (int h = 0; h < 32; ++h) {
        const char* sA = smem + (h & 3) * 32768;
        const char* sB = sA + 16384;
        bf16x8 a[8], b[4];
#pragma unroll
        for (int f = 0; f < 4; ++f) {
            const int r = wrow + (f << 4) + l15;
            a[f] = *(const bf16x8*)(sA + (r << 6) + ((kgrp ^ ((r >> 1) & 3)) << 4));
        }
#pragma unroll
        for (int g = 0; g < 4; ++g) {
            const int r = wcol + (g << 4) + l15;
            b[g] = *(const bf16x8*)(sB + (r << 6) + ((kgrp ^ ((r >> 1) & 3)) << 4));
        }
        if (h < 29) STAGE_HALF(h + 3, 0);
        SBAR();
        asm volatile("s_waitcnt lgkmcnt(0)" ::: "memory");
        __builtin_amdgcn_s_setprio(1);
#pragma unroll
        for (int mi = 0; mi < 4; ++mi)
#pragma unroll
            for (int ni = 0; ni < 4; ++ni)
                acc[mi][ni] = __builtin_amdgcn_mfma_f32_16x16x32_bf16(
                    a[mi], b[ni], acc[mi][ni], 0, 0, 0);
        __builtin_amdgcn_s_setprio(0);
        SBAR();
#pragma unroll
        for (int f = 4; f < 8; ++f) {
            const int r = wrow + (f << 4) + l15;
            a[f] = *(const bf16x8*)(sA + (r << 6) + ((kgrp ^ ((r >> 1) & 3)) << 4));
        }
        if (h < 29) {
            STAGE_HALF(h + 3, 1);
            asm volatile("s_waitcnt vmcnt(8)" ::: "memory");
        } else if (h == 29) {
            asm volatile("s_waitcnt vmcnt(4)" ::: "memory");
        } else if (h == 30) {
            asm volatile("s_waitcnt vmcnt(0)" ::: "memory");
        }
        SBAR();
        asm volatile("s_waitcnt lgkmcnt(0)" ::: "memory");
        __builtin_amdgcn_s_setprio(1);
#pragma unroll
        for (int mi = 4; mi < 8; ++mi)
#pragma unroll
            for (int ni = 0; ni < 4; ++ni)
                acc[mi][ni] = __builtin_amdgcn_mfma_f32_16x16x32_bf16(
                    a[mi], b[ni], acc[mi][ni], 0, 0, 0);
        __builtin_amdgcn_s_setprio(0);
        SBAR();
    }

    const int crow = kgrp << 2;
    float bv[4];
#pragma unroll
    for (int ni = 0; ni < 4; ++ni) bv[ni] = bias[n0 + wcol + (ni << 4) + l15];
#pragma unroll
    for (int mi = 0; mi < 8; ++mi) {
        const int rbase = m0 + wrow + (mi << 4) + crow;
#pragma unroll
        for (int ni = 0; ni < 4; ++ni) {
            const int col = n0 + wcol + (ni << 4) + l15;
#pragma unroll
            for (int r = 0; r < 4; ++r) {
                float v = acc[mi][ni][r] + bv[ni];
                if (mode == 0) v = v > 0.0f ? v : 0.0f;
                outb[(size_t)(rbase + r) * D + col] = f2bf(v);
            }
        }
    }
}

// hb = bf16(LN(hb + vb)) in place  [R8-measured ~15us ≈ HBM roofline]
__global__ __launch_bounds__(256) void resid_ln_b(
    unsigned short* __restrict__ hb, const unsigned short* __restrict__ vb,
    const float* __restrict__ gamma, const float* __restrict__ beta) {
    const int row = blockIdx.x;
    const int t = threadIdx.x;
    unsigned short* hr = hb + (size_t)row * D;
    ushort4 hv = ((const ushort4*)hr)[t];
    ushort4 vv = ((const ushort4*)(vb + (size_t)row * D))[t];
    float4 v;
    v.x = bf2f(hv.x) + bf2f(vv.x); v.y = bf2f(hv.y) + bf2f(vv.y);
    v.z = bf2f(hv.z) + bf2f(vv.z); v.w = bf2f(hv.w) + bf2f(vv.w);
    float s = v.x + v.y + v.z + v.w;
    float s2 = v.x * v.x + v.y * v.y + v.z * v.z + v.w * v.w;
#pragma unroll
    for (int off = 32; off > 0; off >>= 1) {
        s += __shfl_down(s, off);
        s2 += __shfl_down(s2, off);
    }
    __shared__ float red[8];
    const int wid = t >> 6, lane = t & 63;
    if (lane == 0) { red[wid] = s; red[wid + 4] = s2; }
    __syncthreads();
    s = red[0] + red[1] + red[2] + red[3];
    s2 = red[4] + red[5] + red[6] + red[7];
    const float mu = s * (1.0f / D);
    const float var = s2 * (1.0f / D) - mu * mu;
    const float rs = rsqrtf(var + 1e-5f);
    float4 g = ((const float4*)gamma)[t];
    float4 b = ((const float4*)beta)[t];
    ushort4 u;
    u.x = f2bf((v.x - mu) * rs * g.x + b.x);
    u.y = f2bf((v.y - mu) * rs * g.y + b.y);
    u.z = f2bf((v.z - mu) * rs * g.z + b.z);
    u.w = f2bf((v.w - mu) * rs * g.w + b.w);
    ((ushort4*)hr)[t] = u;
}

// out = h + v  (final block)  [R8-measured ~21us ≈ HBM roofline]
__global__ __launch_bounds__(256) void final_add(
    const unsigned short* __restrict__ hb, const unsigned short* __restrict__ vb,
    float* __restrict__ out) {
    const size_t i = (size_t)blockIdx.x * 256 + threadIdx.x;
    ushort4 hv = ((const ushort4*)hb)[i];
    ushort4 vv = ((const ushort4*)vb)[i];
    float4 o;
    o.x = bf2f(hv.x) + bf2f(vv.x); o.y = bf2f(hv.y) + bf2f(vv.y);
    o.z = bf2f(hv.z) + bf2f(vv.z); o.w = bf2f(hv.w) + bf2f(vv.w);
    ((float4*)out)[i] = o;
}

extern "C" void kernel_launch(void* const* d_in, const int* in_sizes, int n_in,
                              void* d_out, int out_size, void* d_ws, size_t ws_size,
                              hipStream_t stream) {
    const float* x      = (const float*)d_in[0];
    const int*   q      = (const int*)d_in[1];
    const float* scales = (const float*)d_in[2];
    const float* biases = (const float*)d_in[3];
    const float* la     = (const float*)d_in[4];
    const float* lb     = (const float*)d_in[5];
    const float* lng    = (const float*)d_in[6];
    const float* lnb    = (const float*)d_in[7];
    float* out = (float*)d_out;

    char* p = (char*)d_ws;
    unsigned short* weff = (unsigned short*)p; p += (size_t)NLAYERS * D * D * 2;  // 37.75MB
    unsigned short* xbA  = (unsigned short*)p; p += (size_t)BATCH * D * 2;        // residual stream
    unsigned short* xbB  = (unsigned short*)p; p += (size_t)BATCH * D * 2;
    unsigned short* xbC  = (unsigned short*)p;
    // loraB aliases xbB..xbC (both dead until the first GEMMs, which run
    // after dequant on the same stream): 37.75MB <= 67.1MB available.
    unsigned short* loraB = xbB;

    lora_gemm<<<NLAYERS * 16, 512, 0, stream>>>(la, lb, loraB);
    dequant<<<2048, 256, 0, stream>>>(q, scales, loraB, weff);
    init_xb<<<BATCH * D / 4 / 256, 256, 0, stream>>>(x, xbA);

    dim3 ggrid(4, 64);
    for (int blk = 0; blk < 6; ++blk) {
        const int li = 3 * blk;
        gemm256<<<ggrid, 512, 0, stream>>>(xbA, weff + (size_t)li * D * D,
                                           biases + (size_t)li * D, xbB, 0);
        gemm256<<<ggrid, 512, 0, stream>>>(xbB, weff + (size_t)(li + 1) * D * D,
                                           biases + (size_t)(li + 1) * D, xbC, 0);
        gemm256<<<ggrid, 512, 0, stream>>>(xbC, weff + (size_t)(li + 2) * D * D,
                                           biases + (size_t)(li + 2) * D, xbB, 1);
        if (blk < 5)
            resid_ln_b<<<BATCH, 256, 0, stream>>>(xbA, xbB,
                                                  lng + (size_t)blk * D, lnb + (size_t)blk * D);
        else
            final_add<<<BATCH * D / 4 / 256, 256, 0, stream>>>(xbA, xbB, out);
    }
}